// Round 1
// baseline (424.399 us; speedup 1.0000x reference)
//
#include <hip/hip_runtime.h>

#define EMBED 1024
#define NHEAD 16
#define HDIM  64
#define BB    2
#define SS    2048

typedef __bf16 bf16x8 __attribute__((ext_vector_type(8)));
typedef float  f32x4  __attribute__((ext_vector_type(4)));

__device__ __forceinline__ unsigned short f2bf(float f) {
  union { float f; unsigned u; } v; v.f = f;
  unsigned r = v.u + 0x7fffu + ((v.u >> 16) & 1u);
  return (unsigned short)(r >> 16);
}

__device__ __forceinline__ void g2l16(const unsigned short* g, unsigned short* l) {
  __builtin_amdgcn_global_load_lds(
      (const __attribute__((address_space(1))) unsigned int*)g,
      (__attribute__((address_space(3))) unsigned int*)l, 16, 0, 0);
}

// ---------------- fp32 -> bf16 convert ----------------
__global__ __launch_bounds__(256) void cvt_kernel(const float* __restrict__ src,
                                                  unsigned short* __restrict__ dst,
                                                  int n4) {
  int i = blockIdx.x * 256 + threadIdx.x;
  if (i < n4) {
    const float4 f = ((const float4*)src)[i];
    ushort4 u;
    u.x = f2bf(f.x); u.y = f2bf(f.y); u.z = f2bf(f.z); u.w = f2bf(f.w);
    ((ushort4*)dst)[i] = u;
  }
}

// ---------------- 128x128 MFMA GEMM: C[m][n] = sum_k A[m][k]*Bm[n][k] ----------------
// EPI 0: m=feature, n=token  -> bf16 out [(b,h,s,d)]   (Q or K projection)
// EPI 1: m=token,  n=feature -> bf16 out [(b,h,d,s)]   (V projection, transposed)
// EPI 2: m=feature, n=token  -> fp32 out [token][1024] (final projection)
template <int EPI>
__global__ __launch_bounds__(256)
void gemm128(const unsigned short* __restrict__ A,
             const unsigned short* __restrict__ Bm,
             const float* __restrict__ bias,
             void* __restrict__ outp) {
  __shared__ unsigned short sA[128 * 64];
  __shared__ unsigned short sB[128 * 64];
  const int tid = threadIdx.x;
  const int l  = tid & 63;
  const int w  = tid >> 6;
  const int lm = l & 15;
  const int qd = l >> 4;
  const int wm = w & 1;
  const int wn = w >> 1;
  const int m0 = blockIdx.y * 128;
  const int n0 = blockIdx.x * 128;

  f32x4 acc[4][4];
#pragma unroll
  for (int i = 0; i < 4; ++i)
#pragma unroll
    for (int j = 0; j < 4; ++j) acc[i][j] = (f32x4){0.f, 0.f, 0.f, 0.f};

  for (int k0 = 0; k0 < EMBED; k0 += 64) {
    // stage A and B tiles (128 rows x 64 k) via async 16B global->LDS,
    // XOR-swizzled source chunk so LDS chunk (r, cs) holds global chunk cs^(r&7)
#pragma unroll
    for (int i = 0; i < 4; ++i) {
      const int t = i * 256 + tid;
      const int r = t >> 3;
      const int c = (t & 7) ^ (r & 7);
      unsigned short* lp = &sA[(i * 256 + (w << 6)) * 8];
      g2l16(A + (m0 + r) * EMBED + k0 + c * 8, lp);
      unsigned short* lp2 = &sB[(i * 256 + (w << 6)) * 8];
      g2l16(Bm + (n0 + r) * EMBED + k0 + c * 8, lp2);
    }
    __syncthreads();
#pragma unroll
    for (int kk = 0; kk < 2; ++kk) {
      bf16x8 af[4], bfr[4];
#pragma unroll
      for (int mi = 0; mi < 4; ++mi) {
        const int R = wm * 64 + mi * 16 + lm;
        const int ch = R * 8 + (((kk << 2) + qd) ^ (R & 7));
        af[mi] = *(const bf16x8*)&sA[ch * 8];
      }
#pragma unroll
      for (int ni = 0; ni < 4; ++ni) {
        const int R = wn * 64 + ni * 16 + lm;
        const int ch = R * 8 + (((kk << 2) + qd) ^ (R & 7));
        bfr[ni] = *(const bf16x8*)&sB[ch * 8];
      }
#pragma unroll
      for (int mi = 0; mi < 4; ++mi)
#pragma unroll
        for (int ni = 0; ni < 4; ++ni)
          acc[mi][ni] = __builtin_amdgcn_mfma_f32_16x16x32_bf16(
              af[mi], bfr[ni], acc[mi][ni], 0, 0, 0);
    }
    __syncthreads();
  }

#pragma unroll
  for (int mi = 0; mi < 4; ++mi) {
#pragma unroll
    for (int ni = 0; ni < 4; ++ni) {
      f32x4 v = acc[mi][ni];
      const int mb = m0 + wm * 64 + mi * 16 + qd * 4;  // rows: mb..mb+3
      const int n  = n0 + wn * 64 + ni * 16 + lm;
      if (EPI == 0) {
        const float4 bv = *(const float4*)&bias[mb];
        const int h = mb >> 6, d0 = mb & 63;
        const int b = n >> 11, s = n & 2047;
        ushort4 u;
        u.x = f2bf(v.x + bv.x); u.y = f2bf(v.y + bv.y);
        u.z = f2bf(v.z + bv.z); u.w = f2bf(v.w + bv.w);
        unsigned short* O = (unsigned short*)outp;
        *(ushort4*)&O[(((b * NHEAD + h) * SS) + s) * HDIM + d0] = u;
      } else if (EPI == 1) {
        const float bv = bias[n];
        const int b = mb >> 11, s = mb & 2047;
        const int h = n >> 6, d = n & 63;
        ushort4 u;
        u.x = f2bf(v.x + bv); u.y = f2bf(v.y + bv);
        u.z = f2bf(v.z + bv); u.w = f2bf(v.w + bv);
        unsigned short* O = (unsigned short*)outp;
        *(ushort4*)&O[(((b * NHEAD + h) * HDIM) + d) * SS + s] = u;
      } else {
        const float4 bv = *(const float4*)&bias[mb];
        float* O = (float*)outp;
        float4 o;
        o.x = v.x + bv.x; o.y = v.y + bv.y; o.z = v.z + bv.z; o.w = v.w + bv.w;
        *(float4*)&O[n * EMBED + mb] = o;
      }
    }
  }
}

// ---------------- flash attention: 1 wave = 16 q rows, 32-key blocks ----------------
__global__ __launch_bounds__(256)
void attn_kernel(const unsigned short* __restrict__ Q,
                 const unsigned short* __restrict__ K,
                 const unsigned short* __restrict__ VT,
                 const int* __restrict__ mask,
                 unsigned short* __restrict__ Obuf) {
  __shared__ unsigned short P[4][16 * 40];  // per-wave P tile, stride 40 breaks conflicts
  const int tid = threadIdx.x;
  const int l = tid & 63, w = tid >> 6;
  const int lm = l & 15, qd = l >> 4;
  const int b = blockIdx.z, h = blockIdx.y;
  const int q0 = blockIdx.x * 64 + w * 16;
  const unsigned short* Qh = Q + ((b * NHEAD + h) * SS) * HDIM;
  const unsigned short* Kh = K + ((b * NHEAD + h) * SS) * HDIM;
  const unsigned short* Vh = VT + ((b * NHEAD + h) * HDIM) * SS;
  const int* mrow = mask + b * SS;

  const bf16x8 qf0 = *(const bf16x8*)&Qh[(q0 + lm) * HDIM + qd * 8];
  const bf16x8 qf1 = *(const bf16x8*)&Qh[(q0 + lm) * HDIM + 32 + qd * 8];

  f32x4 Od[4];
  float mrun[4], lrun[4];
#pragma unroll
  for (int i = 0; i < 4; ++i) { Od[i] = (f32x4){0.f,0.f,0.f,0.f}; mrun[i] = -1e38f; lrun[i] = 0.f; }
  const float sc = 0.125f * 1.4426950408889634f;  // 1/sqrt(64) * log2(e)

  for (int kb = 0; kb < SS; kb += 32) {
    f32x4 s0 = (f32x4){0.f,0.f,0.f,0.f}, s1 = (f32x4){0.f,0.f,0.f,0.f};
    const bf16x8 k00 = *(const bf16x8*)&Kh[(kb + lm) * HDIM + qd * 8];
    const bf16x8 k01 = *(const bf16x8*)&Kh[(kb + lm) * HDIM + 32 + qd * 8];
    const bf16x8 k10 = *(const bf16x8*)&Kh[(kb + 16 + lm) * HDIM + qd * 8];
    const bf16x8 k11 = *(const bf16x8*)&Kh[(kb + 16 + lm) * HDIM + 32 + qd * 8];
    s0 = __builtin_amdgcn_mfma_f32_16x16x32_bf16(qf0, k00, s0, 0, 0, 0);
    s0 = __builtin_amdgcn_mfma_f32_16x16x32_bf16(qf1, k01, s0, 0, 0, 0);
    s1 = __builtin_amdgcn_mfma_f32_16x16x32_bf16(qf0, k10, s1, 0, 0, 0);
    s1 = __builtin_amdgcn_mfma_f32_16x16x32_bf16(qf1, k11, s1, 0, 0, 0);
    const bool ok0 = mrow[kb + lm] != 0;
    const bool ok1 = mrow[kb + 16 + lm] != 0;
    float alpha[4];
#pragma unroll
    for (int r = 0; r < 4; ++r) {
      const float a = ok0 ? s0[r] * sc : -1e30f;
      const float c = ok1 ? s1[r] * sc : -1e30f;
      float v = fmaxf(a, c);
      v = fmaxf(v, __shfl_xor(v, 1, 16));
      v = fmaxf(v, __shfl_xor(v, 2, 16));
      v = fmaxf(v, __shfl_xor(v, 4, 16));
      v = fmaxf(v, __shfl_xor(v, 8, 16));
      const float mn = fmaxf(mrun[r], v);
      alpha[r] = exp2f(mrun[r] - mn);
      mrun[r] = mn;
      const float p0 = exp2f(a - mn), p1 = exp2f(c - mn);
      s0[r] = p0; s1[r] = p1;
      float rs = p0 + p1;
      rs += __shfl_xor(rs, 1, 16);
      rs += __shfl_xor(rs, 2, 16);
      rs += __shfl_xor(rs, 4, 16);
      rs += __shfl_xor(rs, 8, 16);
      lrun[r] = lrun[r] * alpha[r] + rs;
    }
    unsigned short* Pw = P[w];
#pragma unroll
    for (int r = 0; r < 4; ++r) {
      Pw[(qd * 4 + r) * 40 + lm] = f2bf(s0[r]);
      Pw[(qd * 4 + r) * 40 + 16 + lm] = f2bf(s1[r]);
    }
#pragma unroll
    for (int dt = 0; dt < 4; ++dt)
#pragma unroll
      for (int r = 0; r < 4; ++r) Od[dt][r] *= alpha[r];
    // wave-synchronous P round-trip: drain LDS writes, block compiler reordering
    asm volatile("s_waitcnt lgkmcnt(0)" ::: "memory");
    const bf16x8 pf = *(const bf16x8*)&Pw[lm * 40 + qd * 8];
#pragma unroll
    for (int dt = 0; dt < 4; ++dt) {
      const bf16x8 vf = *(const bf16x8*)&Vh[(dt * 16 + lm) * SS + kb + qd * 8];
      Od[dt] = __builtin_amdgcn_mfma_f32_16x16x32_bf16(pf, vf, Od[dt], 0, 0, 0);
    }
    asm volatile("s_waitcnt lgkmcnt(0)" ::: "memory");
  }
  float rinv[4];
#pragma unroll
  for (int r = 0; r < 4; ++r) rinv[r] = 1.f / lrun[r];
#pragma unroll
  for (int dt = 0; dt < 4; ++dt)
#pragma unroll
    for (int r = 0; r < 4; ++r) {
      const int s = q0 + qd * 4 + r;
      Obuf[(b * SS + s) * EMBED + h * HDIM + dt * 16 + lm] = f2bf(Od[dt][r] * rinv[r]);
    }
}

extern "C" void kernel_launch(void* const* d_in, const int* in_sizes, int n_in,
                              void* d_out, int out_size, void* d_ws, size_t ws_size,
                              hipStream_t stream) {
  const float* x  = (const float*)d_in[0];
  const int* mask = (const int*)d_in[1];
  const float* Wq = (const float*)d_in[2];
  const float* bq = (const float*)d_in[3];
  const float* Wk = (const float*)d_in[4];
  const float* bk = (const float*)d_in[5];
  const float* Wv = (const float*)d_in[6];
  const float* bv = (const float*)d_in[7];
  const float* Wo = (const float*)d_in[8];
  const float* bo = (const float*)d_in[9];
  float* out = (float*)d_out;

  char* ws = (char*)d_ws;
  unsigned short* xb  = (unsigned short*)(ws);                    // 8 MB
  unsigned short* Wqb = (unsigned short*)(ws + 8u * 1024 * 1024); // 2 MB each
  unsigned short* Wkb = Wqb + 1024 * 1024;
  unsigned short* Wvb = Wkb + 1024 * 1024;
  unsigned short* Wob = Wvb + 1024 * 1024;
  unsigned short* Qb  = (unsigned short*)(ws + 16u * 1024 * 1024); // 8 MB
  unsigned short* Kb  = Qb + 4u * 1024 * 1024;                     // 8 MB
  unsigned short* VTb = Kb + 4u * 1024 * 1024;                     // 8 MB
  unsigned short* Ob  = VTb + 4u * 1024 * 1024;                    // 8 MB (end: 48 MB)

  cvt_kernel<<<4096, 256, 0, stream>>>(x,  xb,  1024 * 1024);
  cvt_kernel<<<1024, 256, 0, stream>>>(Wq, Wqb, 256 * 1024);
  cvt_kernel<<<1024, 256, 0, stream>>>(Wk, Wkb, 256 * 1024);
  cvt_kernel<<<1024, 256, 0, stream>>>(Wv, Wvb, 256 * 1024);
  cvt_kernel<<<1024, 256, 0, stream>>>(Wo, Wob, 256 * 1024);

  const dim3 blk(256);
  gemm128<0><<<dim3(32, 8), blk, 0, stream>>>(Wqb, xb, bq, Qb);   // Q: A=Wq (feat), B=x (tok)
  gemm128<0><<<dim3(32, 8), blk, 0, stream>>>(Wkb, xb, bk, Kb);   // K
  gemm128<1><<<dim3(8, 32), blk, 0, stream>>>(xb, Wvb, bv, VTb);  // V -> V^T layout
  attn_kernel<<<dim3(32, 16, 2), blk, 0, stream>>>(Qb, Kb, VTb, mask, Ob);
  gemm128<2><<<dim3(32, 8), blk, 0, stream>>>(Wob, Ob, bo, out);  // out projection, fp32
}

// Round 2
// 400.393 us; speedup vs baseline: 1.0600x; 1.0600x over previous
//
#include <hip/hip_runtime.h>

#define EMBED 1024
#define NHEAD 16
#define HDIM  64
#define BB    2
#define SS    2048

typedef __bf16 bf16x8 __attribute__((ext_vector_type(8)));
typedef float  f32x4  __attribute__((ext_vector_type(4)));

__device__ __forceinline__ unsigned short f2bf(float f) {
  union { float f; unsigned u; } v; v.f = f;
  unsigned r = v.u + 0x7fffu + ((v.u >> 16) & 1u);
  return (unsigned short)(r >> 16);
}

__device__ __forceinline__ void g2l16(const unsigned short* g, unsigned short* l) {
  __builtin_amdgcn_global_load_lds(
      (const __attribute__((address_space(1))) unsigned int*)g,
      (__attribute__((address_space(3))) unsigned int*)l, 16, 0, 0);
}

// ---------------- fused fp32 -> bf16 convert of x + 4 weights ----------------
// region 0: x (1M float4), regions 1..4: Wq,Wk,Wv,Wo (256K float4 each)
__global__ __launch_bounds__(256)
void cvt5_kernel(const float* __restrict__ x,  const float* __restrict__ Wq,
                 const float* __restrict__ Wk, const float* __restrict__ Wv,
                 const float* __restrict__ Wo,
                 unsigned short* __restrict__ xb,  unsigned short* __restrict__ Wqb,
                 unsigned short* __restrict__ Wkb, unsigned short* __restrict__ Wvb,
                 unsigned short* __restrict__ Wob) {
  const int i = blockIdx.x * 256 + threadIdx.x;  // 0 .. 2M-1 float4s
  const float* src;
  unsigned short* dst;
  int j;
  if (i < (1 << 20)) {
    src = x; dst = xb; j = i;
  } else {
    const int t = i - (1 << 20);
    const int r = t >> 18;
    j = t & ((1 << 18) - 1);
    src = (r == 0) ? Wq : (r == 1) ? Wk : (r == 2) ? Wv : Wo;
    dst = (r == 0) ? Wqb : (r == 1) ? Wkb : (r == 2) ? Wvb : Wob;
  }
  const float4 f = ((const float4*)src)[j];
  ushort4 u;
  u.x = f2bf(f.x); u.y = f2bf(f.y); u.z = f2bf(f.z); u.w = f2bf(f.w);
  ((ushort4*)dst)[j] = u;
}

// ---------------- shared GEMM core: C[m][n] = sum_k A[m][k]*Bm[n][k] -----------
// acc indexed [mi][ni]; caller handles epilogue.
template <typename EpiFn>
__device__ __forceinline__
void gemm_core(const unsigned short* __restrict__ A,
               const unsigned short* __restrict__ Bm,
               int m0, int n0, EpiFn epi) {
  __shared__ unsigned short sA[128 * 64];
  __shared__ unsigned short sB[128 * 64];
  const int tid = threadIdx.x;
  const int l  = tid & 63;
  const int w  = tid >> 6;
  const int lm = l & 15;
  const int qd = l >> 4;
  const int wm = w & 1;
  const int wn = w >> 1;

  f32x4 acc[4][4];
#pragma unroll
  for (int i = 0; i < 4; ++i)
#pragma unroll
    for (int j = 0; j < 4; ++j) acc[i][j] = (f32x4){0.f, 0.f, 0.f, 0.f};

  for (int k0 = 0; k0 < EMBED; k0 += 64) {
#pragma unroll
    for (int i = 0; i < 4; ++i) {
      const int t = i * 256 + tid;
      const int r = t >> 3;
      const int c = (t & 7) ^ (r & 7);
      unsigned short* lp = &sA[(i * 256 + (w << 6)) * 8];
      g2l16(A + (m0 + r) * EMBED + k0 + c * 8, lp);
      unsigned short* lp2 = &sB[(i * 256 + (w << 6)) * 8];
      g2l16(Bm + (n0 + r) * EMBED + k0 + c * 8, lp2);
    }
    __syncthreads();
#pragma unroll
    for (int kk = 0; kk < 2; ++kk) {
      bf16x8 af[4], bfr[4];
#pragma unroll
      for (int mi = 0; mi < 4; ++mi) {
        const int R = wm * 64 + mi * 16 + lm;
        const int ch = R * 8 + (((kk << 2) + qd) ^ (R & 7));
        af[mi] = *(const bf16x8*)&sA[ch * 8];
      }
#pragma unroll
      for (int ni = 0; ni < 4; ++ni) {
        const int R = wn * 64 + ni * 16 + lm;
        const int ch = R * 8 + (((kk << 2) + qd) ^ (R & 7));
        bfr[ni] = *(const bf16x8*)&sB[ch * 8];
      }
#pragma unroll
      for (int mi = 0; mi < 4; ++mi)
#pragma unroll
        for (int ni = 0; ni < 4; ++ni)
          acc[mi][ni] = __builtin_amdgcn_mfma_f32_16x16x32_bf16(
              af[mi], bfr[ni], acc[mi][ni], 0, 0, 0);
    }
    __syncthreads();
  }

#pragma unroll
  for (int mi = 0; mi < 4; ++mi)
#pragma unroll
    for (int ni = 0; ni < 4; ++ni) {
      const int mb = m0 + wm * 64 + mi * 16 + qd * 4;  // rows mb..mb+3
      const int n  = n0 + wn * 64 + ni * 16 + lm;
      epi(acc[mi][ni], mb, n);
    }
}

// ---------------- fused Q/K/V projection ----------------
// z=0: Q = Wq·x^T epilogue->(b,h,s,d) bf16 *pre-scaled by 1/8*log2e
// z=1: K = Wk·x^T epilogue->(b,h,s,d) bf16
// z=2: V = x·Wv^T epilogue->(b,h,d,s) bf16 (transposed for PV)
__global__ __launch_bounds__(256)
void gemm_qkv(const unsigned short* __restrict__ xb,
              const unsigned short* __restrict__ Wqb,
              const unsigned short* __restrict__ Wkb,
              const unsigned short* __restrict__ Wvb,
              const float* __restrict__ bq, const float* __restrict__ bk,
              const float* __restrict__ bv,
              unsigned short* __restrict__ Qb, unsigned short* __restrict__ Kb,
              unsigned short* __restrict__ VTb) {
  const int z = blockIdx.y;
  const int flat = blockIdx.x;
  if (z < 2) {
    const unsigned short* A = z ? Wkb : Wqb;
    const float* bias = z ? bk : bq;
    unsigned short* O = z ? Kb : Qb;
    const float scale = z ? 1.0f : 0.125f * 1.4426950408889634f;
    const int m0 = (flat >> 5) * 128;  // feature
    const int n0 = (flat & 31) * 128;  // token
    gemm_core(A, xb, m0, n0, [&](const f32x4& v, int mb, int n) {
      const float4 bvv = *(const float4*)&bias[mb];
      const int h = mb >> 6, d0 = mb & 63;
      const int b = n >> 11, s = n & 2047;
      ushort4 u;
      u.x = f2bf((v.x + bvv.x) * scale); u.y = f2bf((v.y + bvv.y) * scale);
      u.z = f2bf((v.z + bvv.z) * scale); u.w = f2bf((v.w + bvv.w) * scale);
      *(ushort4*)&O[(((b * NHEAD + h) * SS) + s) * HDIM + d0] = u;
    });
  } else {
    const int m0 = (flat & 31) * 128;  // token
    const int n0 = (flat >> 5) * 128;  // feature
    gemm_core(xb, Wvb, m0, n0, [&](const f32x4& v, int mb, int n) {
      const float bvv = bv[n];
      const int b = mb >> 11, s = mb & 2047;
      const int h = n >> 6, d = n & 63;
      ushort4 u;
      u.x = f2bf(v.x + bvv); u.y = f2bf(v.y + bvv);
      u.z = f2bf(v.z + bvv); u.w = f2bf(v.w + bvv);
      *(ushort4*)&VTb[(((b * NHEAD + h) * HDIM) + d) * SS + s] = u;
    });
  }
}

// ---------------- output projection: fp32 out ----------------
__global__ __launch_bounds__(256)
void gemm_out(const unsigned short* __restrict__ Wob,
              const unsigned short* __restrict__ Ob,
              const float* __restrict__ bo, float* __restrict__ out) {
  const int m0 = blockIdx.y * 128;  // feature
  const int n0 = blockIdx.x * 128;  // token
  gemm_core(Wob, Ob, m0, n0, [&](const f32x4& v, int mb, int n) {
    const float4 bvv = *(const float4*)&bo[mb];
    float4 o;
    o.x = v.x + bvv.x; o.y = v.y + bvv.y; o.z = v.z + bvv.z; o.w = v.w + bvv.w;
    *(float4*)&out[n * EMBED + mb] = o;
  });
}

// ---------------- flash attention, S^T orientation, no-shift softmax ----------
// 1 wave = 16 q rows; 32-key blocks. Q is pre-scaled by (1/8)*log2(e), so
// p = exp2(s) directly. Row-sum is per-lane (each lane's scores share one
// q-row) -> no in-loop shuffles.
__global__ __launch_bounds__(256)
void attn_kernel(const unsigned short* __restrict__ Q,
                 const unsigned short* __restrict__ K,
                 const unsigned short* __restrict__ VT,
                 const int* __restrict__ mask,
                 unsigned short* __restrict__ Obuf) {
  __shared__ unsigned short P[4][16 * 40];  // [wave][qrow][key0..31], stride 40
  const int tid = threadIdx.x;
  const int l = tid & 63, w = tid >> 6;
  const int lm = l & 15, qd = l >> 4;
  const int b = blockIdx.z, h = blockIdx.y;
  const int q0 = blockIdx.x * 64 + w * 16;
  const unsigned short* Qh = Q + ((b * NHEAD + h) * SS) * HDIM;
  const unsigned short* Kh = K + ((b * NHEAD + h) * SS) * HDIM;
  const unsigned short* Vh = VT + ((b * NHEAD + h) * HDIM) * SS;
  const int* mrow = mask + b * SS;

  const bf16x8 qf0 = *(const bf16x8*)&Qh[(q0 + lm) * HDIM + qd * 8];
  const bf16x8 qf1 = *(const bf16x8*)&Qh[(q0 + lm) * HDIM + 32 + qd * 8];

  f32x4 Od[4];
#pragma unroll
  for (int i = 0; i < 4; ++i) Od[i] = (f32x4){0.f, 0.f, 0.f, 0.f};
  float lsum = 0.f;
  unsigned short* Pw = P[w];

  for (int kb = 0; kb < SS; kb += 32) {
    // S^T = K . Q^T : C row = key (qd*4+r), col = q-row (lm)
    const bf16x8 k00 = *(const bf16x8*)&Kh[(kb + lm) * HDIM + qd * 8];
    const bf16x8 k01 = *(const bf16x8*)&Kh[(kb + lm) * HDIM + 32 + qd * 8];
    const bf16x8 k10 = *(const bf16x8*)&Kh[(kb + 16 + lm) * HDIM + qd * 8];
    const bf16x8 k11 = *(const bf16x8*)&Kh[(kb + 16 + lm) * HDIM + 32 + qd * 8];
    f32x4 s0 = (f32x4){0.f,0.f,0.f,0.f}, s1 = (f32x4){0.f,0.f,0.f,0.f};
    s0 = __builtin_amdgcn_mfma_f32_16x16x32_bf16(k00, qf0, s0, 0, 0, 0);
    s0 = __builtin_amdgcn_mfma_f32_16x16x32_bf16(k01, qf1, s0, 0, 0, 0);
    s1 = __builtin_amdgcn_mfma_f32_16x16x32_bf16(k10, qf0, s1, 0, 0, 0);
    s1 = __builtin_amdgcn_mfma_f32_16x16x32_bf16(k11, qf1, s1, 0, 0, 0);

    const int4 mk0 = *(const int4*)&mrow[kb + qd * 4];
    const int4 mk1 = *(const int4*)&mrow[kb + 16 + qd * 4];
    float p0[4], p1[4];
    p0[0] = mk0.x ? exp2f(s0[0]) : 0.f;
    p0[1] = mk0.y ? exp2f(s0[1]) : 0.f;
    p0[2] = mk0.z ? exp2f(s0[2]) : 0.f;
    p0[3] = mk0.w ? exp2f(s0[3]) : 0.f;
    p1[0] = mk1.x ? exp2f(s1[0]) : 0.f;
    p1[1] = mk1.y ? exp2f(s1[1]) : 0.f;
    p1[2] = mk1.z ? exp2f(s1[2]) : 0.f;
    p1[3] = mk1.w ? exp2f(s1[3]) : 0.f;
    lsum += ((p0[0] + p0[1]) + (p0[2] + p0[3])) +
            ((p1[0] + p1[1]) + (p1[2] + p1[3]));

    ushort4 u0, u1;
    u0.x = f2bf(p0[0]); u0.y = f2bf(p0[1]); u0.z = f2bf(p0[2]); u0.w = f2bf(p0[3]);
    u1.x = f2bf(p1[0]); u1.y = f2bf(p1[1]); u1.z = f2bf(p1[2]); u1.w = f2bf(p1[3]);
    // lane (qd,lm) owns keys qd*4..qd*4+3 (and +16) of q-row lm: b64 writes
    *(ushort4*)&Pw[lm * 40 + qd * 4] = u0;
    *(ushort4*)&Pw[lm * 40 + 16 + qd * 4] = u1;

    asm volatile("s_waitcnt lgkmcnt(0)" ::: "memory");
    const bf16x8 pf = *(const bf16x8*)&Pw[lm * 40 + qd * 8];  // A[m=qrow][k=key]
#pragma unroll
    for (int dt = 0; dt < 4; ++dt) {
      const bf16x8 vf = *(const bf16x8*)&Vh[(dt * 16 + lm) * SS + kb + qd * 8];
      Od[dt] = __builtin_amdgcn_mfma_f32_16x16x32_bf16(pf, vf, Od[dt], 0, 0, 0);
    }
    asm volatile("s_waitcnt lgkmcnt(0)" ::: "memory");
  }

  // lsum at lane (qd,lm) covers keys {qd*4..+3, 16+qd*4..+3} of q-row lm;
  // reduce across qd (lanes lm, lm+16, lm+32, lm+48):
  lsum += __shfl_xor(lsum, 16);
  lsum += __shfl_xor(lsum, 32);
  // Od C-layout rows are q-rows qd*4+r -> fetch l for that row from lane qd*4+r
  float rinv[4];
#pragma unroll
  for (int r = 0; r < 4; ++r) rinv[r] = 1.f / __shfl(lsum, qd * 4 + r);
#pragma unroll
  for (int dt = 0; dt < 4; ++dt)
#pragma unroll
    for (int r = 0; r < 4; ++r) {
      const int s = q0 + qd * 4 + r;
      Obuf[(b * SS + s) * EMBED + h * HDIM + dt * 16 + lm] = f2bf(Od[dt][r] * rinv[r]);
    }
}

extern "C" void kernel_launch(void* const* d_in, const int* in_sizes, int n_in,
                              void* d_out, int out_size, void* d_ws, size_t ws_size,
                              hipStream_t stream) {
  const float* x  = (const float*)d_in[0];
  const int* mask = (const int*)d_in[1];
  const float* Wq = (const float*)d_in[2];
  const float* bq = (const float*)d_in[3];
  const float* Wk = (const float*)d_in[4];
  const float* bk = (const float*)d_in[5];
  const float* Wv = (const float*)d_in[6];
  const float* bv = (const float*)d_in[7];
  const float* Wo = (const float*)d_in[8];
  const float* bo = (const float*)d_in[9];
  float* out = (float*)d_out;

  char* ws = (char*)d_ws;
  unsigned short* xb  = (unsigned short*)(ws);                    // 8 MB
  unsigned short* Wqb = (unsigned short*)(ws + 8u * 1024 * 1024); // 2 MB each
  unsigned short* Wkb = Wqb + 1024 * 1024;
  unsigned short* Wvb = Wkb + 1024 * 1024;
  unsigned short* Wob = Wvb + 1024 * 1024;
  unsigned short* Qb  = (unsigned short*)(ws + 16u * 1024 * 1024); // 8 MB
  unsigned short* Kb  = Qb + 4u * 1024 * 1024;                     // 8 MB
  unsigned short* VTb = Kb + 4u * 1024 * 1024;                     // 8 MB
  unsigned short* Ob  = VTb + 4u * 1024 * 1024;                    // 8 MB (end: 48 MB)

  cvt5_kernel<<<8192, 256, 0, stream>>>(x, Wq, Wk, Wv, Wo, xb, Wqb, Wkb, Wvb, Wob);
  gemm_qkv<<<dim3(256, 3), 256, 0, stream>>>(xb, Wqb, Wkb, Wvb, bq, bk, bv,
                                             Qb, Kb, VTb);
  attn_kernel<<<dim3(32, 16, 2), 256, 0, stream>>>(Qb, Kb, VTb, mask, Ob);
  gemm_out<<<dim3(32, 8), 256, 0, stream>>>(Wob, Ob, bo, out);
}

// Round 4
// 230.854 us; speedup vs baseline: 1.8384x; 1.7344x over previous
//
#include <hip/hip_runtime.h>

#define EMBED 1024
#define NHEAD 16
#define HDIM  64
#define BB    2
#define SS    2048

typedef __bf16 bf16x8 __attribute__((ext_vector_type(8)));
typedef float  f32x4  __attribute__((ext_vector_type(4)));
typedef _Float16 f16x4 __attribute__((ext_vector_type(4)));
typedef __fp16 hf16x2 __attribute__((ext_vector_type(2)));

__device__ __forceinline__ unsigned short f2bf(float f) {
  union { float f; unsigned u; } v; v.f = f;
  unsigned r = v.u + 0x7fffu + ((v.u >> 16) & 1u);
  return (unsigned short)(r >> 16);
}

__device__ __forceinline__ unsigned short f2h(float f) {
  union { _Float16 h; unsigned short u; } t;
  t.h = (_Float16)f;
  return t.u;
}

__device__ __forceinline__ void g2l16(const unsigned short* g, unsigned short* l) {
  __builtin_amdgcn_global_load_lds(
      (const __attribute__((address_space(1))) unsigned int*)g,
      (__attribute__((address_space(3))) unsigned int*)l, 16, 0, 0);
}

// ---------------- fused fp32 -> bf16 convert of x + 4 weights ----------------
__global__ __launch_bounds__(256)
void cvt5_kernel(const float* __restrict__ x,  const float* __restrict__ Wq,
                 const float* __restrict__ Wk, const float* __restrict__ Wv,
                 const float* __restrict__ Wo,
                 unsigned short* __restrict__ xb,  unsigned short* __restrict__ Wqb,
                 unsigned short* __restrict__ Wkb, unsigned short* __restrict__ Wvb,
                 unsigned short* __restrict__ Wob) {
  const int i = blockIdx.x * 256 + threadIdx.x;  // 0 .. 2M-1 float4s
  const float* src;
  unsigned short* dst;
  int j;
  if (i < (1 << 20)) {
    src = x; dst = xb; j = i;
  } else {
    const int t = i - (1 << 20);
    const int r = t >> 18;
    j = t & ((1 << 18) - 1);
    src = (r == 0) ? Wq : (r == 1) ? Wk : (r == 2) ? Wv : Wo;
    dst = (r == 0) ? Wqb : (r == 1) ? Wkb : (r == 2) ? Wvb : Wob;
  }
  const float4 f = ((const float4*)src)[j];
  ushort4 u;
  u.x = f2bf(f.x); u.y = f2bf(f.y); u.z = f2bf(f.z); u.w = f2bf(f.w);
  ((ushort4*)dst)[j] = u;
}

// ---------------- shared GEMM core: C[m][n] = sum_k A[m][k]*Bm[n][k] -----------
template <typename EpiFn>
__device__ __forceinline__
void gemm_core(const unsigned short* __restrict__ A,
               const unsigned short* __restrict__ Bm,
               int m0, int n0, EpiFn epi) {
  __shared__ unsigned short sA[128 * 64];
  __shared__ unsigned short sB[128 * 64];
  const int tid = threadIdx.x;
  const int l  = tid & 63;
  const int w  = tid >> 6;
  const int lm = l & 15;
  const int qd = l >> 4;
  const int wm = w & 1;
  const int wn = w >> 1;

  f32x4 acc[4][4];
#pragma unroll
  for (int i = 0; i < 4; ++i)
#pragma unroll
    for (int j = 0; j < 4; ++j) acc[i][j] = (f32x4){0.f, 0.f, 0.f, 0.f};

  for (int k0 = 0; k0 < EMBED; k0 += 64) {
#pragma unroll
    for (int i = 0; i < 4; ++i) {
      const int t = i * 256 + tid;
      const int r = t >> 3;
      const int c = (t & 7) ^ (r & 7);
      unsigned short* lp = &sA[(i * 256 + (w << 6)) * 8];
      g2l16(A + (m0 + r) * EMBED + k0 + c * 8, lp);
      unsigned short* lp2 = &sB[(i * 256 + (w << 6)) * 8];
      g2l16(Bm + (n0 + r) * EMBED + k0 + c * 8, lp2);
    }
    __syncthreads();
#pragma unroll
    for (int kk = 0; kk < 2; ++kk) {
      bf16x8 af[4], bfr[4];
#pragma unroll
      for (int mi = 0; mi < 4; ++mi) {
        const int R = wm * 64 + mi * 16 + lm;
        const int ch = R * 8 + (((kk << 2) + qd) ^ (R & 7));
        af[mi] = *(const bf16x8*)&sA[ch * 8];
      }
#pragma unroll
      for (int ni = 0; ni < 4; ++ni) {
        const int R = wn * 64 + ni * 16 + lm;
        const int ch = R * 8 + (((kk << 2) + qd) ^ (R & 7));
        bfr[ni] = *(const bf16x8*)&sB[ch * 8];
      }
#pragma unroll
      for (int mi = 0; mi < 4; ++mi)
#pragma unroll
        for (int ni = 0; ni < 4; ++ni)
          acc[mi][ni] = __builtin_amdgcn_mfma_f32_16x16x32_bf16(
              af[mi], bfr[ni], acc[mi][ni], 0, 0, 0);
    }
    __syncthreads();
  }

#pragma unroll
  for (int mi = 0; mi < 4; ++mi)
#pragma unroll
    for (int ni = 0; ni < 4; ++ni) {
      const int mb = m0 + wm * 64 + mi * 16 + qd * 4;  // rows mb..mb+3
      const int n  = n0 + wn * 64 + ni * 16 + lm;
      epi(acc[mi][ni], mb, n);
    }
}

// ---------------- fused Q/K/V projection ----------------
// z=0: Q = Wq·x^T ->(b,h,s,d) bf16, pre-scaled by (1/8)*log2(e)
// z=1: K = Wk·x^T ->(b,h,s,d) bf16
// z=2: V = x·Wv^T ->(b,h,d,s) fp16 (transposed, fp16 for K=16 PV MFMA)
__global__ __launch_bounds__(256)
void gemm_qkv(const unsigned short* __restrict__ xb,
              const unsigned short* __restrict__ Wqb,
              const unsigned short* __restrict__ Wkb,
              const unsigned short* __restrict__ Wvb,
              const float* __restrict__ bq, const float* __restrict__ bk,
              const float* __restrict__ bv,
              unsigned short* __restrict__ Qb, unsigned short* __restrict__ Kb,
              unsigned short* __restrict__ VTb) {
  const int z = blockIdx.y;
  const int flat = blockIdx.x;
  if (z < 2) {
    const unsigned short* A = z ? Wkb : Wqb;
    const float* bias = z ? bk : bq;
    unsigned short* O = z ? Kb : Qb;
    const float scale = z ? 1.0f : 0.125f * 1.4426950408889634f;
    const int m0 = (flat >> 5) * 128;  // feature
    const int n0 = (flat & 31) * 128;  // token
    gemm_core(A, xb, m0, n0, [&](const f32x4& v, int mb, int n) {
      const float4 bvv = *(const float4*)&bias[mb];
      const int h = mb >> 6, d0 = mb & 63;
      const int b = n >> 11, s = n & 2047;
      ushort4 u;
      u.x = f2bf((v.x + bvv.x) * scale); u.y = f2bf((v.y + bvv.y) * scale);
      u.z = f2bf((v.z + bvv.z) * scale); u.w = f2bf((v.w + bvv.w) * scale);
      *(ushort4*)&O[(((b * NHEAD + h) * SS) + s) * HDIM + d0] = u;
    });
  } else {
    const int m0 = (flat & 31) * 128;  // token
    const int n0 = (flat >> 5) * 128;  // feature
    gemm_core(xb, Wvb, m0, n0, [&](const f32x4& v, int mb, int n) {
      const float bvv = bv[n];
      const int b = mb >> 11, s = mb & 2047;
      const int h = n >> 6, d = n & 63;
      ushort4 u;
      u.x = f2h(v.x + bvv); u.y = f2h(v.y + bvv);
      u.z = f2h(v.z + bvv); u.w = f2h(v.w + bvv);
      *(ushort4*)&VTb[(((b * NHEAD + h) * HDIM) + d) * SS + s] = u;
    });
  }
}

// ---------------- output projection: fp32 out ----------------
__global__ __launch_bounds__(256)
void gemm_out(const unsigned short* __restrict__ Wob,
              const unsigned short* __restrict__ Ob,
              const float* __restrict__ bo, float* __restrict__ out) {
  const int m0 = blockIdx.y * 128;  // feature
  const int n0 = blockIdx.x * 128;  // token
  gemm_core(Wob, Ob, m0, n0, [&](const f32x4& v, int mb, int n) {
    const float4 bvv = *(const float4*)&bo[mb];
    float4 o;
    o.x = v.x + bvv.x; o.y = v.y + bvv.y; o.z = v.z + bvv.z; o.w = v.w + bvv.w;
    *(float4*)&out[n * EMBED + mb] = o;
  });
}

// ---------------- flash attention, LDS-staged, register P ----------
// Block = 64 q-rows (4 waves x 16). Iterate 64-key tiles:
//  - K-tile (64x64 bf16) and VT-tile (64 dim x 64 key fp16) staged via
//    global_load_lds, XOR-chunk swizzle, shared by all 4 waves.
//  - S^T = K·Q^T (K=32 bf16 MFMA); exp2; pack to fp16 in-register.
//  - S^T's C-layout IS the B-fragment layout of mfma_f32_16x16x16f16,
//    so PV runs as O^T = VT·P^T with zero LDS round-trip / shuffles.
__global__ __launch_bounds__(256)
void attn_kernel(const unsigned short* __restrict__ Q,
                 const unsigned short* __restrict__ K,
                 const unsigned short* __restrict__ VT,
                 const int* __restrict__ mask,
                 unsigned short* __restrict__ Obuf) {
  __shared__ unsigned short sK[64 * 64];  // bf16, row=key, chunk-swizzled
  __shared__ unsigned short sV[64 * 64];  // fp16, row=dim, chunk-swizzled
  const int tid = threadIdx.x;
  const int l = tid & 63, w = tid >> 6;
  const int lm = l & 15, qd = l >> 4;
  const int b = blockIdx.z, h = blockIdx.y;
  const int q0 = blockIdx.x * 64 + w * 16;
  const unsigned short* Qh = Q + ((b * NHEAD + h) * SS) * HDIM;
  const unsigned short* Kh = K + ((b * NHEAD + h) * SS) * HDIM;
  const unsigned short* Vh = VT + ((b * NHEAD + h) * HDIM) * SS;
  const int* mrow = mask + b * SS;

  const bf16x8 qf0 = *(const bf16x8*)&Qh[(q0 + lm) * HDIM + qd * 8];
  const bf16x8 qf1 = *(const bf16x8*)&Qh[(q0 + lm) * HDIM + 32 + qd * 8];

  f32x4 Od[4];
#pragma unroll
  for (int i = 0; i < 4; ++i) Od[i] = (f32x4){0.f, 0.f, 0.f, 0.f};
  float lsum = 0.f;

  for (int kb = 0; kb < SS; kb += 64) {
    // stage K-tile + VT-tile: 512 chunks each of 16B, 2 rounds per buffer
#pragma unroll
    for (int i = 0; i < 2; ++i) {
      const int t = i * 256 + tid;
      const int r = t >> 3;
      const int c = (t & 7) ^ (r & 7);
      g2l16(Kh + (kb + r) * HDIM + c * 8, &sK[(i * 256 + (w << 6)) * 8]);
      g2l16(Vh + r * SS + kb + c * 8, &sV[(i * 256 + (w << 6)) * 8]);
    }
    __syncthreads();

    int4 mk[4];
#pragma unroll
    for (int j = 0; j < 4; ++j) mk[j] = *(const int4*)&mrow[kb + j * 16 + qd * 4];

    // S^T tiles: s[j] C-layout: key = j*16 + qd*4 + r, q = lm
    f32x4 s[4];
#pragma unroll
    for (int j = 0; j < 4; ++j) {
      const int R = j * 16 + lm;
      const bf16x8 k0 = *(const bf16x8*)&sK[(R * 8 + (qd ^ (lm & 7))) * 8];
      const bf16x8 k1 = *(const bf16x8*)&sK[(R * 8 + ((4 + qd) ^ (lm & 7))) * 8];
      f32x4 t0 = (f32x4){0.f, 0.f, 0.f, 0.f};
      t0 = __builtin_amdgcn_mfma_f32_16x16x32_bf16(k0, qf0, t0, 0, 0, 0);
      t0 = __builtin_amdgcn_mfma_f32_16x16x32_bf16(k1, qf1, t0, 0, 0, 0);
      s[j] = t0;
    }

    // exp2 + mask + fp16 pack: pf[j] is the ready-made B-frag of 16x16x16f16
    f16x4 pf[4];
#pragma unroll
    for (int j = 0; j < 4; ++j) {
      const float p0 = mk[j].x ? exp2f(s[j][0]) : 0.f;
      const float p1 = mk[j].y ? exp2f(s[j][1]) : 0.f;
      const float p2 = mk[j].z ? exp2f(s[j][2]) : 0.f;
      const float p3 = mk[j].w ? exp2f(s[j][3]) : 0.f;
      lsum += (p0 + p1) + (p2 + p3);
      union { hf16x2 v[2]; f16x4 f; } pk;
      pk.v[0] = __builtin_amdgcn_cvt_pkrtz(p0, p1);
      pk.v[1] = __builtin_amdgcn_cvt_pkrtz(p2, p3);
      pf[j] = pk.f;
    }

    // O^T += VT-frag(dt,j) x pf[j]  (A[m=dim][k=key], B[k=key][n=q])
#pragma unroll
    for (int dt = 0; dt < 4; ++dt) {
      const int row = dt * 16 + lm;
#pragma unroll
      for (int j = 0; j < 4; ++j) {
        const int ch = (j * 2 + (qd >> 1)) ^ (lm & 7);
        const f16x4 vf = *(const f16x4*)&sV[row * 64 + ch * 8 + (qd & 1) * 4];
        Od[dt] = __builtin_amdgcn_mfma_f32_16x16x16f16(vf, pf[j], Od[dt], 0, 0, 0);
      }
    }
    __syncthreads();
  }

  // lane (qd,lm): lsum covers keys {j*16+qd*4+r} of q-row lm -> reduce over qd
  lsum += __shfl_xor(lsum, 16);
  lsum += __shfl_xor(lsum, 32);
  const float rinv = 1.f / lsum;
  // O^T C-layout: lane (qd,lm) holds q=lm, dims dt*16 + qd*4 + r
#pragma unroll
  for (int dt = 0; dt < 4; ++dt) {
    ushort4 u;
    u.x = f2bf(Od[dt][0] * rinv); u.y = f2bf(Od[dt][1] * rinv);
    u.z = f2bf(Od[dt][2] * rinv); u.w = f2bf(Od[dt][3] * rinv);
    *(ushort4*)&Obuf[(b * SS + q0 + lm) * EMBED + h * HDIM + dt * 16 + qd * 4] = u;
  }
}

extern "C" void kernel_launch(void* const* d_in, const int* in_sizes, int n_in,
                              void* d_out, int out_size, void* d_ws, size_t ws_size,
                              hipStream_t stream) {
  const float* x  = (const float*)d_in[0];
  const int* mask = (const int*)d_in[1];
  const float* Wq = (const float*)d_in[2];
  const float* bq = (const float*)d_in[3];
  const float* Wk = (const float*)d_in[4];
  const float* bk = (const float*)d_in[5];
  const float* Wv = (const float*)d_in[6];
  const float* bv = (const float*)d_in[7];
  const float* Wo = (const float*)d_in[8];
  const float* bo = (const float*)d_in[9];
  float* out = (float*)d_out;

  char* ws = (char*)d_ws;
  unsigned short* xb  = (unsigned short*)(ws);                    // 8 MB
  unsigned short* Wqb = (unsigned short*)(ws + 8u * 1024 * 1024); // 2 MB each
  unsigned short* Wkb = Wqb + 1024 * 1024;
  unsigned short* Wvb = Wkb + 1024 * 1024;
  unsigned short* Wob = Wvb + 1024 * 1024;
  unsigned short* Qb  = (unsigned short*)(ws + 16u * 1024 * 1024); // 8 MB
  unsigned short* Kb  = Qb + 4u * 1024 * 1024;                     // 8 MB
  unsigned short* VTb = Kb + 4u * 1024 * 1024;                     // 8 MB (fp16)
  unsigned short* Ob  = VTb + 4u * 1024 * 1024;                    // 8 MB (end: 48 MB)

  cvt5_kernel<<<8192, 256, 0, stream>>>(x, Wq, Wk, Wv, Wo, xb, Wqb, Wkb, Wvb, Wob);
  gemm_qkv<<<dim3(256, 3), 256, 0, stream>>>(xb, Wqb, Wkb, Wvb, bq, bk, bv,
                                             Qb, Kb, VTb);
  attn_kernel<<<dim3(32, 16, 2), 256, 0, stream>>>(Qb, Kb, VTb, mask, Ob);
  gemm_out<<<dim3(32, 8), 256, 0, stream>>>(Wob, Ob, bo, out);
}

// Round 5
// 219.774 us; speedup vs baseline: 1.9311x; 1.0504x over previous
//
#include <hip/hip_runtime.h>

#define EMBED 1024
#define NHEAD 16
#define HDIM  64
#define BB    2
#define SS    2048

typedef __bf16 bf16x8 __attribute__((ext_vector_type(8)));
typedef float  f32x4  __attribute__((ext_vector_type(4)));
typedef _Float16 f16x4 __attribute__((ext_vector_type(4)));
typedef __fp16 hf16x2 __attribute__((ext_vector_type(2)));

#if defined(__has_builtin)
#if __has_builtin(__builtin_amdgcn_exp2f)
#define EXP2(x) __builtin_amdgcn_exp2f(x)
#else
#define EXP2(x) exp2f(x)
#endif
#else
#define EXP2(x) exp2f(x)
#endif

__device__ __forceinline__ unsigned short f2bf(float f) {
  union { float f; unsigned u; } v; v.f = f;
  unsigned r = v.u + 0x7fffu + ((v.u >> 16) & 1u);
  return (unsigned short)(r >> 16);
}

__device__ __forceinline__ unsigned short f2h(float f) {
  union { _Float16 h; unsigned short u; } t;
  t.h = (_Float16)f;
  return t.u;
}

__device__ __forceinline__ void g2l16(const unsigned short* g, unsigned short* l) {
  __builtin_amdgcn_global_load_lds(
      (const __attribute__((address_space(1))) unsigned int*)g,
      (__attribute__((address_space(3))) unsigned int*)l, 16, 0, 0);
}

// ------- fused fp32->bf16 convert of x + 4 weights, + maskbias build -------
__global__ __launch_bounds__(256)
void cvt5_kernel(const float* __restrict__ x,  const float* __restrict__ Wq,
                 const float* __restrict__ Wk, const float* __restrict__ Wv,
                 const float* __restrict__ Wo, const int* __restrict__ mask,
                 unsigned short* __restrict__ xb,  unsigned short* __restrict__ Wqb,
                 unsigned short* __restrict__ Wkb, unsigned short* __restrict__ Wvb,
                 unsigned short* __restrict__ Wob, float* __restrict__ mbias) {
  const int i = blockIdx.x * 256 + threadIdx.x;
  if (i < (1 << 21)) {
    const float* src;
    unsigned short* dst;
    int j;
    if (i < (1 << 20)) {
      src = x; dst = xb; j = i;
    } else {
      const int t = i - (1 << 20);
      const int r = t >> 18;
      j = t & ((1 << 18) - 1);
      src = (r == 0) ? Wq : (r == 1) ? Wk : (r == 2) ? Wv : Wo;
      dst = (r == 0) ? Wqb : (r == 1) ? Wkb : (r == 2) ? Wvb : Wob;
    }
    const float4 f = ((const float4*)src)[j];
    ushort4 u;
    u.x = f2bf(f.x); u.y = f2bf(f.y); u.z = f2bf(f.z); u.w = f2bf(f.w);
    ((ushort4*)dst)[j] = u;
  } else {
    const int j = i - (1 << 21);  // 0..1023 int4 groups of mask
    const int4 m = ((const int4*)mask)[j];
    float4 o;
    o.x = m.x ? 0.f : -1e30f; o.y = m.y ? 0.f : -1e30f;
    o.z = m.z ? 0.f : -1e30f; o.w = m.w ? 0.f : -1e30f;
    ((float4*)mbias)[j] = o;
  }
}

// ------- shared GEMM core: C[m][n] = sum_k A[m][k]*Bm[n][k] -------
template <typename EpiFn>
__device__ __forceinline__
void gemm_core(const unsigned short* __restrict__ A,
               const unsigned short* __restrict__ Bm,
               int m0, int n0, EpiFn epi) {
  __shared__ unsigned short sA[128 * 64];
  __shared__ unsigned short sB[128 * 64];
  const int tid = threadIdx.x;
  const int l  = tid & 63;
  const int w  = tid >> 6;
  const int lm = l & 15;
  const int qd = l >> 4;
  const int wm = w & 1;
  const int wn = w >> 1;

  f32x4 acc[4][4];
#pragma unroll
  for (int i = 0; i < 4; ++i)
#pragma unroll
    for (int j = 0; j < 4; ++j) acc[i][j] = (f32x4){0.f, 0.f, 0.f, 0.f};

  for (int k0 = 0; k0 < EMBED; k0 += 64) {
#pragma unroll
    for (int i = 0; i < 4; ++i) {
      const int t = i * 256 + tid;
      const int r = t >> 3;
      const int c = (t & 7) ^ (r & 7);
      g2l16(A + (m0 + r) * EMBED + k0 + c * 8, &sA[(i * 256 + (w << 6)) * 8]);
      g2l16(Bm + (n0 + r) * EMBED + k0 + c * 8, &sB[(i * 256 + (w << 6)) * 8]);
    }
    __syncthreads();
#pragma unroll
    for (int kk = 0; kk < 2; ++kk) {
      bf16x8 af[4], bfr[4];
#pragma unroll
      for (int mi = 0; mi < 4; ++mi) {
        const int R = wm * 64 + mi * 16 + lm;
        const int ch = R * 8 + (((kk << 2) + qd) ^ (R & 7));
        af[mi] = *(const bf16x8*)&sA[ch * 8];
      }
#pragma unroll
      for (int ni = 0; ni < 4; ++ni) {
        const int R = wn * 64 + ni * 16 + lm;
        const int ch = R * 8 + (((kk << 2) + qd) ^ (R & 7));
        bfr[ni] = *(const bf16x8*)&sB[ch * 8];
      }
#pragma unroll
      for (int mi = 0; mi < 4; ++mi)
#pragma unroll
        for (int ni = 0; ni < 4; ++ni)
          acc[mi][ni] = __builtin_amdgcn_mfma_f32_16x16x32_bf16(
              af[mi], bfr[ni], acc[mi][ni], 0, 0, 0);
    }
    __syncthreads();
  }

#pragma unroll
  for (int mi = 0; mi < 4; ++mi)
#pragma unroll
    for (int ni = 0; ni < 4; ++ni) {
      const int mb = m0 + wm * 64 + mi * 16 + qd * 4;  // rows mb..mb+3
      const int n  = n0 + wn * 64 + ni * 16 + lm;
      epi(acc[mi][ni], mb, n);
    }
}

// supertile decode for L2 locality: 16 consecutive blocks = 2a x 8b tile grp
__device__ __forceinline__ void decode_tile(int flat, int& a0, int& b0) {
  const int sub = flat & 15;
  const int g = flat >> 4;           // 0..15
  a0 = ((g >> 2) * 2 + (sub >> 3));  // 0..7  (feature dim / 128)
  b0 = ((g & 3) * 8 + (sub & 7));    // 0..31 (token dim / 128)
}

// ------- fused Q/K/V projection -------
// z=0: Q = Wq·x^T ->(b,h,s,d) bf16, pre-scaled by (1/8)*log2(e)
// z=1: K = Wk·x^T ->(b,h,s,d) bf16
// z=2: V = x·Wv^T ->(b,h,d,s) fp16 (transposed, for PV MFMA)
__global__ __launch_bounds__(256)
void gemm_qkv(const unsigned short* __restrict__ xb,
              const unsigned short* __restrict__ Wqb,
              const unsigned short* __restrict__ Wkb,
              const unsigned short* __restrict__ Wvb,
              const float* __restrict__ bq, const float* __restrict__ bk,
              const float* __restrict__ bv,
              unsigned short* __restrict__ Qb, unsigned short* __restrict__ Kb,
              unsigned short* __restrict__ VTb) {
  const int z = blockIdx.y;
  int a0, b0;
  decode_tile(blockIdx.x, a0, b0);
  if (z < 2) {
    const unsigned short* A = z ? Wkb : Wqb;
    const float* bias = z ? bk : bq;
    unsigned short* O = z ? Kb : Qb;
    const float scale = z ? 1.0f : 0.125f * 1.4426950408889634f;
    gemm_core(A, xb, a0 * 128, b0 * 128, [&](const f32x4& v, int mb, int n) {
      const float4 bvv = *(const float4*)&bias[mb];
      const int h = mb >> 6, d0 = mb & 63;
      const int b = n >> 11, s = n & 2047;
      ushort4 u;
      u.x = f2bf((v.x + bvv.x) * scale); u.y = f2bf((v.y + bvv.y) * scale);
      u.z = f2bf((v.z + bvv.z) * scale); u.w = f2bf((v.w + bvv.w) * scale);
      *(ushort4*)&O[(((b * NHEAD + h) * SS) + s) * HDIM + d0] = u;
    });
  } else {
    gemm_core(xb, Wvb, b0 * 128, a0 * 128, [&](const f32x4& v, int mb, int n) {
      const float bvv = bv[n];
      const int b = mb >> 11, s = mb & 2047;
      const int h = n >> 6, d = n & 63;
      ushort4 u;
      u.x = f2h(v.x + bvv); u.y = f2h(v.y + bvv);
      u.z = f2h(v.z + bvv); u.w = f2h(v.w + bvv);
      *(ushort4*)&VTb[(((b * NHEAD + h) * HDIM) + d) * SS + s] = u;
    });
  }
}

// ------- output projection: fp32 out -------
__global__ __launch_bounds__(256)
void gemm_out(const unsigned short* __restrict__ Wob,
              const unsigned short* __restrict__ Ob,
              const float* __restrict__ bo, float* __restrict__ out) {
  int a0, b0;
  decode_tile(blockIdx.x, a0, b0);
  gemm_core(Wob, Ob, a0 * 128, b0 * 128, [&](const f32x4& v, int mb, int n) {
    const float4 bvv = *(const float4*)&bo[mb];
    float4 o;
    o.x = v.x + bvv.x; o.y = v.y + bvv.y; o.z = v.z + bvv.z; o.w = v.w + bvv.w;
    *(float4*)&out[n * EMBED + mb] = o;
  });
}

// ------- flash attention: 32 q-rows/wave, LDS K/V shared by both q-groups ----
// Block = 128 q (4 waves x 32). 64-key tiles. Mask folded into QK acc-init
// (maskbias = 0 / -1e30, exp2 -> 0). K-frag and V-frag LDS reads are issued
// once per tile and reused by both 16-q groups -> LDS-port cycles per score
// halve vs R4 (the measured bottleneck).
__global__ __launch_bounds__(256)
void attn_kernel(const unsigned short* __restrict__ Q,
                 const unsigned short* __restrict__ K,
                 const unsigned short* __restrict__ VT,
                 const float* __restrict__ mbias,
                 unsigned short* __restrict__ Obuf) {
  __shared__ unsigned short sK[64 * 64];  // bf16, row=key, chunk-swizzled
  __shared__ unsigned short sV[64 * 64];  // fp16, row=dim, chunk-swizzled
  const int tid = threadIdx.x;
  const int l = tid & 63, w = tid >> 6;
  const int lm = l & 15, qd = l >> 4;
  const int b = blockIdx.z, h = blockIdx.y;
  const int q0 = blockIdx.x * 128 + w * 32;  // wave: q0 .. q0+31
  const unsigned short* Qh = Q + ((b * NHEAD + h) * SS) * HDIM;
  const unsigned short* Kh = K + ((b * NHEAD + h) * SS) * HDIM;
  const unsigned short* Vh = VT + ((b * NHEAD + h) * HDIM) * SS;
  const float* mb = mbias + b * SS;

  bf16x8 qf[2][2];
#pragma unroll
  for (int g = 0; g < 2; ++g) {
    qf[g][0] = *(const bf16x8*)&Qh[(q0 + g * 16 + lm) * HDIM + qd * 8];
    qf[g][1] = *(const bf16x8*)&Qh[(q0 + g * 16 + lm) * HDIM + 32 + qd * 8];
  }

  f32x4 Od[2][4];
#pragma unroll
  for (int g = 0; g < 2; ++g)
#pragma unroll
    for (int i = 0; i < 4; ++i) Od[g][i] = (f32x4){0.f, 0.f, 0.f, 0.f};
  float lsum[2] = {0.f, 0.f};

  for (int kb = 0; kb < SS; kb += 64) {
#pragma unroll
    for (int i = 0; i < 2; ++i) {
      const int t = i * 256 + tid;
      const int r = t >> 3;
      const int c = (t & 7) ^ (r & 7);
      g2l16(Kh + (kb + r) * HDIM + c * 8, &sK[(i * 256 + (w << 6)) * 8]);
      g2l16(Vh + r * SS + kb + c * 8, &sV[(i * 256 + (w << 6)) * 8]);
    }
    __syncthreads();

    // S^T per j-tile: C row = key (j*16+qd*4+r), col = q (lm). K-frags read
    // ONCE, used by both q-groups. Mask enters as the accumulator init.
    f16x4 pf[2][4];
#pragma unroll
    for (int j = 0; j < 4; ++j) {
      const int R = j * 16 + lm;
      const bf16x8 k0 = *(const bf16x8*)&sK[(R * 8 + (qd ^ (lm & 7))) * 8];
      const bf16x8 k1 = *(const bf16x8*)&sK[(R * 8 + ((4 + qd) ^ (lm & 7))) * 8];
      const float4 bj = *(const float4*)&mb[kb + j * 16 + qd * 4];
      const f32x4 binit = (f32x4){bj.x, bj.y, bj.z, bj.w};
#pragma unroll
      for (int g = 0; g < 2; ++g) {
        f32x4 t0 = binit;
        t0 = __builtin_amdgcn_mfma_f32_16x16x32_bf16(k0, qf[g][0], t0, 0, 0, 0);
        t0 = __builtin_amdgcn_mfma_f32_16x16x32_bf16(k1, qf[g][1], t0, 0, 0, 0);
        const float p0 = EXP2(t0[0]);
        const float p1 = EXP2(t0[1]);
        const float p2 = EXP2(t0[2]);
        const float p3 = EXP2(t0[3]);
        lsum[g] += (p0 + p1) + (p2 + p3);
        union { hf16x2 v[2]; f16x4 f; } pk;
        pk.v[0] = __builtin_amdgcn_cvt_pkrtz(p0, p1);
        pk.v[1] = __builtin_amdgcn_cvt_pkrtz(p2, p3);
        pf[g][j] = pk.f;
      }
    }

    // O^T += V-frag x P-frag; V-frag read ONCE, feeds both q-groups.
#pragma unroll
    for (int dt = 0; dt < 4; ++dt) {
      const int row = dt * 16 + lm;
#pragma unroll
      for (int j = 0; j < 4; ++j) {
        const int ch = (j * 2 + (qd >> 1)) ^ (lm & 7);
        const f16x4 vf = *(const f16x4*)&sV[row * 64 + ch * 8 + (qd & 1) * 4];
#pragma unroll
        for (int g = 0; g < 2; ++g)
          Od[g][dt] = __builtin_amdgcn_mfma_f32_16x16x16f16(vf, pf[g][j],
                                                            Od[g][dt], 0, 0, 0);
      }
    }
    __syncthreads();
  }

#pragma unroll
  for (int g = 0; g < 2; ++g) {
    float ls = lsum[g];
    ls += __shfl_xor(ls, 16);
    ls += __shfl_xor(ls, 32);
    const float rinv = 1.f / ls;
#pragma unroll
    for (int dt = 0; dt < 4; ++dt) {
      ushort4 u;
      u.x = f2bf(Od[g][dt][0] * rinv); u.y = f2bf(Od[g][dt][1] * rinv);
      u.z = f2bf(Od[g][dt][2] * rinv); u.w = f2bf(Od[g][dt][3] * rinv);
      *(ushort4*)&Obuf[(b * SS + q0 + g * 16 + lm) * EMBED + h * HDIM +
                       dt * 16 + qd * 4] = u;
    }
  }
}

extern "C" void kernel_launch(void* const* d_in, const int* in_sizes, int n_in,
                              void* d_out, int out_size, void* d_ws, size_t ws_size,
                              hipStream_t stream) {
  const float* x  = (const float*)d_in[0];
  const int* mask = (const int*)d_in[1];
  const float* Wq = (const float*)d_in[2];
  const float* bq = (const float*)d_in[3];
  const float* Wk = (const float*)d_in[4];
  const float* bk = (const float*)d_in[5];
  const float* Wv = (const float*)d_in[6];
  const float* bv = (const float*)d_in[7];
  const float* Wo = (const float*)d_in[8];
  const float* bo = (const float*)d_in[9];
  float* out = (float*)d_out;

  char* ws = (char*)d_ws;
  unsigned short* xb  = (unsigned short*)(ws);                    // 8 MB
  unsigned short* Wqb = (unsigned short*)(ws + 8u * 1024 * 1024); // 2 MB each
  unsigned short* Wkb = Wqb + 1024 * 1024;
  unsigned short* Wvb = Wkb + 1024 * 1024;
  unsigned short* Wob = Wvb + 1024 * 1024;
  unsigned short* Qb  = (unsigned short*)(ws + 16u * 1024 * 1024); // 8 MB
  unsigned short* Kb  = Qb + 4u * 1024 * 1024;                     // 8 MB
  unsigned short* VTb = Kb + 4u * 1024 * 1024;                     // 8 MB (fp16)
  unsigned short* Ob  = VTb + 4u * 1024 * 1024;                    // 8 MB
  float* mbb = (float*)(ws + 48u * 1024 * 1024);                   // 16 KB

  cvt5_kernel<<<8196, 256, 0, stream>>>(x, Wq, Wk, Wv, Wo, mask,
                                        xb, Wqb, Wkb, Wvb, Wob, mbb);
  gemm_qkv<<<dim3(256, 3), 256, 0, stream>>>(xb, Wqb, Wkb, Wvb, bq, bk, bv,
                                             Qb, Kb, VTb);
  attn_kernel<<<dim3(16, 16, 2), 256, 0, stream>>>(Qb, Kb, VTb, mbb, Ob);
  gemm_out<<<256, 256, 0, stream>>>(Wob, Ob, bo, out);
}

// Round 6
// 218.496 us; speedup vs baseline: 1.9424x; 1.0059x over previous
//
#include <hip/hip_runtime.h>

#define EMBED 1024
#define NHEAD 16
#define HDIM  64
#define BB    2
#define SS    2048

typedef __bf16 bf16x8 __attribute__((ext_vector_type(8)));
typedef float  f32x4  __attribute__((ext_vector_type(4)));
typedef _Float16 f16x4 __attribute__((ext_vector_type(4)));
typedef __fp16 hf16x2 __attribute__((ext_vector_type(2)));

#if defined(__has_builtin)
#if __has_builtin(__builtin_amdgcn_exp2f)
#define EXP2(x) __builtin_amdgcn_exp2f(x)
#else
#define EXP2(x) exp2f(x)
#endif
#else
#define EXP2(x) exp2f(x)
#endif

__device__ __forceinline__ unsigned short f2bf(float f) {
  union { float f; unsigned u; } v; v.f = f;
  unsigned r = v.u + 0x7fffu + ((v.u >> 16) & 1u);
  return (unsigned short)(r >> 16);
}

__device__ __forceinline__ float bf2f(unsigned short u) {
  union { unsigned u; float f; } v; v.u = ((unsigned)u) << 16;
  return v.f;
}

__device__ __forceinline__ unsigned short f2h(float f) {
  union { _Float16 h; unsigned short u; } t;
  t.h = (_Float16)f;
  return t.u;
}

__device__ __forceinline__ void g2l16(const unsigned short* g, unsigned short* l) {
  __builtin_amdgcn_global_load_lds(
      (const __attribute__((address_space(1))) unsigned int*)g,
      (__attribute__((address_space(3))) unsigned int*)l, 16, 0, 0);
}

// ------- fused fp32->bf16 convert of x + 4 weights, + maskbias build -------
__global__ __launch_bounds__(256)
void cvt5_kernel(const float* __restrict__ x,  const float* __restrict__ Wq,
                 const float* __restrict__ Wk, const float* __restrict__ Wv,
                 const float* __restrict__ Wo, const int* __restrict__ mask,
                 unsigned short* __restrict__ xb,  unsigned short* __restrict__ Wqb,
                 unsigned short* __restrict__ Wkb, unsigned short* __restrict__ Wvb,
                 unsigned short* __restrict__ Wob, float* __restrict__ mbias) {
  const int i = blockIdx.x * 256 + threadIdx.x;
  if (i < (1 << 21)) {
    const float* src;
    unsigned short* dst;
    int j;
    if (i < (1 << 20)) {
      src = x; dst = xb; j = i;
    } else {
      const int t = i - (1 << 20);
      const int r = t >> 18;
      j = t & ((1 << 18) - 1);
      src = (r == 0) ? Wq : (r == 1) ? Wk : (r == 2) ? Wv : Wo;
      dst = (r == 0) ? Wqb : (r == 1) ? Wkb : (r == 2) ? Wvb : Wob;
    }
    const float4 f = ((const float4*)src)[j];
    ushort4 u;
    u.x = f2bf(f.x); u.y = f2bf(f.y); u.z = f2bf(f.z); u.w = f2bf(f.w);
    ((ushort4*)dst)[j] = u;
  } else {
    const int j = i - (1 << 21);  // 0..1023 int4 groups of mask
    const int4 m = ((const int4*)mask)[j];
    float4 o;
    o.x = m.x ? 0.f : -1e30f; o.y = m.y ? 0.f : -1e30f;
    o.z = m.z ? 0.f : -1e30f; o.w = m.w ? 0.f : -1e30f;
    ((float4*)mbias)[j] = o;
  }
}

// ------- shared GEMM core: C[m][n] = sum_k A[m][k]*Bm[n][k] -------
template <typename EpiFn>
__device__ __forceinline__
void gemm_core(const unsigned short* __restrict__ A,
               const unsigned short* __restrict__ Bm,
               int m0, int n0, EpiFn epi) {
  __shared__ unsigned short sA[128 * 64];
  __shared__ unsigned short sB[128 * 64];
  const int tid = threadIdx.x;
  const int l  = tid & 63;
  const int w  = tid >> 6;
  const int lm = l & 15;
  const int qd = l >> 4;
  const int wm = w & 1;
  const int wn = w >> 1;

  f32x4 acc[4][4];
#pragma unroll
  for (int i = 0; i < 4; ++i)
#pragma unroll
    for (int j = 0; j < 4; ++j) acc[i][j] = (f32x4){0.f, 0.f, 0.f, 0.f};

  for (int k0 = 0; k0 < EMBED; k0 += 64) {
#pragma unroll
    for (int i = 0; i < 4; ++i) {
      const int t = i * 256 + tid;
      const int r = t >> 3;
      const int c = (t & 7) ^ (r & 7);
      g2l16(A + (m0 + r) * EMBED + k0 + c * 8, &sA[(i * 256 + (w << 6)) * 8]);
      g2l16(Bm + (n0 + r) * EMBED + k0 + c * 8, &sB[(i * 256 + (w << 6)) * 8]);
    }
    __syncthreads();
#pragma unroll
    for (int kk = 0; kk < 2; ++kk) {
      bf16x8 af[4], bfr[4];
#pragma unroll
      for (int mi = 0; mi < 4; ++mi) {
        const int R = wm * 64 + mi * 16 + lm;
        const int ch = R * 8 + (((kk << 2) + qd) ^ (R & 7));
        af[mi] = *(const bf16x8*)&sA[ch * 8];
      }
#pragma unroll
      for (int ni = 0; ni < 4; ++ni) {
        const int R = wn * 64 + ni * 16 + lm;
        const int ch = R * 8 + (((kk << 2) + qd) ^ (R & 7));
        bfr[ni] = *(const bf16x8*)&sB[ch * 8];
      }
#pragma unroll
      for (int mi = 0; mi < 4; ++mi)
#pragma unroll
        for (int ni = 0; ni < 4; ++ni)
          acc[mi][ni] = __builtin_amdgcn_mfma_f32_16x16x32_bf16(
              af[mi], bfr[ni], acc[mi][ni], 0, 0, 0);
    }
    __syncthreads();
  }

#pragma unroll
  for (int mi = 0; mi < 4; ++mi)
#pragma unroll
    for (int ni = 0; ni < 4; ++ni) {
      const int mb = m0 + wm * 64 + mi * 16 + qd * 4;  // rows mb..mb+3
      const int n  = n0 + wn * 64 + ni * 16 + lm;
      epi(acc[mi][ni], mb, n);
    }
}

// supertile decode for L2 locality: 16 consecutive blocks = 2a x 8b tile grp
__device__ __forceinline__ void decode_tile(int flat, int& a0, int& b0) {
  const int sub = flat & 15;
  const int g = flat >> 4;           // 0..15
  a0 = ((g >> 2) * 2 + (sub >> 3));  // 0..7  (feature dim / 128)
  b0 = ((g & 3) * 8 + (sub & 7));    // 0..31 (token dim / 128)
}

// ------- fused Q/K/V projection -------
// z=0: Q = Wq·x^T ->(b,h,s,d) bf16, pre-scaled by (1/8)*log2(e)
// z=1: K = Wk·x^T ->(b,h,s,d) bf16
// z=2: V = x·Wv^T ->(b,h,d,s) fp16 (transposed, for PV MFMA)
__global__ __launch_bounds__(256)
void gemm_qkv(const unsigned short* __restrict__ xb,
              const unsigned short* __restrict__ Wqb,
              const unsigned short* __restrict__ Wkb,
              const unsigned short* __restrict__ Wvb,
              const float* __restrict__ bq, const float* __restrict__ bk,
              const float* __restrict__ bv,
              unsigned short* __restrict__ Qb, unsigned short* __restrict__ Kb,
              unsigned short* __restrict__ VTb) {
  const int z = blockIdx.y;
  int a0, b0;
  decode_tile(blockIdx.x, a0, b0);
  if (z < 2) {
    const unsigned short* A = z ? Wkb : Wqb;
    const float* bias = z ? bk : bq;
    unsigned short* O = z ? Kb : Qb;
    const float scale = z ? 1.0f : 0.125f * 1.4426950408889634f;
    gemm_core(A, xb, a0 * 128, b0 * 128, [&](const f32x4& v, int mb, int n) {
      const float4 bvv = *(const float4*)&bias[mb];
      const int h = mb >> 6, d0 = mb & 63;
      const int b = n >> 11, s = n & 2047;
      ushort4 u;
      u.x = f2bf((v.x + bvv.x) * scale); u.y = f2bf((v.y + bvv.y) * scale);
      u.z = f2bf((v.z + bvv.z) * scale); u.w = f2bf((v.w + bvv.w) * scale);
      *(ushort4*)&O[(((b * NHEAD + h) * SS) + s) * HDIM + d0] = u;
    });
  } else {
    gemm_core(xb, Wvb, b0 * 128, a0 * 128, [&](const f32x4& v, int mb, int n) {
      const float bvv = bv[n];
      const int b = mb >> 11, s = mb & 2047;
      const int h = n >> 6, d = n & 63;
      ushort4 u;
      u.x = f2h(v.x + bvv); u.y = f2h(v.y + bvv);
      u.z = f2h(v.z + bvv); u.w = f2h(v.w + bvv);
      *(ushort4*)&VTb[(((b * NHEAD + h) * HDIM) + d) * SS + s] = u;
    });
  }
}

// ------- output projection: fp32 out -------
__global__ __launch_bounds__(256)
void gemm_out(const unsigned short* __restrict__ Wob,
              const unsigned short* __restrict__ Ob,
              const float* __restrict__ bo, float* __restrict__ out) {
  int a0, b0;
  decode_tile(blockIdx.x, a0, b0);
  gemm_core(Wob, Ob, a0 * 128, b0 * 128, [&](const f32x4& v, int mb, int n) {
    const float4 bvv = *(const float4*)&bo[mb];
    float4 o;
    o.x = v.x + bvv.x; o.y = v.y + bvv.y; o.z = v.z + bvv.z; o.w = v.w + bvv.w;
    *(float4*)&out[n * EMBED + mb] = o;
  });
}

// ------- flash attention, key-split x2: 32 q/wave, partial (O,l) per split ----
// grid (16 qtiles, 16 heads, b*2+split). Each block does 16 64-key tiles.
// Partials are additive (no max-shift): O = (P0+P1)/(l0+l1) in combine_kernel.
__global__ __launch_bounds__(256)
void attn_kernel(const unsigned short* __restrict__ Q,
                 const unsigned short* __restrict__ K,
                 const unsigned short* __restrict__ VT,
                 const float* __restrict__ mbias,
                 unsigned short* __restrict__ Opart,
                 float* __restrict__ Lpart) {
  __shared__ unsigned short sK[64 * 64];  // bf16, row=key, chunk-swizzled
  __shared__ unsigned short sV[64 * 64];  // fp16, row=dim, chunk-swizzled
  const int tid = threadIdx.x;
  const int l = tid & 63, w = tid >> 6;
  const int lm = l & 15, qd = l >> 4;
  const int b = blockIdx.z & 1, sp = blockIdx.z >> 1, h = blockIdx.y;
  const int q0 = blockIdx.x * 128 + w * 32;  // wave: q0 .. q0+31
  const unsigned short* Qh = Q + ((b * NHEAD + h) * SS) * HDIM;
  const unsigned short* Kh = K + ((b * NHEAD + h) * SS) * HDIM;
  const unsigned short* Vh = VT + ((b * NHEAD + h) * HDIM) * SS;
  const float* mb = mbias + b * SS;
  unsigned short* Op = Opart + sp * (BB * SS * EMBED);
  float* Lp = Lpart + sp * (BB * NHEAD * SS);

  bf16x8 qf[2][2];
#pragma unroll
  for (int g = 0; g < 2; ++g) {
    qf[g][0] = *(const bf16x8*)&Qh[(q0 + g * 16 + lm) * HDIM + qd * 8];
    qf[g][1] = *(const bf16x8*)&Qh[(q0 + g * 16 + lm) * HDIM + 32 + qd * 8];
  }

  f32x4 Od[2][4];
#pragma unroll
  for (int g = 0; g < 2; ++g)
#pragma unroll
    for (int i = 0; i < 4; ++i) Od[g][i] = (f32x4){0.f, 0.f, 0.f, 0.f};
  float lsum[2] = {0.f, 0.f};

  const int kend = sp * (SS / 2) + (SS / 2);
  for (int kb = sp * (SS / 2); kb < kend; kb += 64) {
#pragma unroll
    for (int i = 0; i < 2; ++i) {
      const int t = i * 256 + tid;
      const int r = t >> 3;
      const int c = (t & 7) ^ (r & 7);
      g2l16(Kh + (kb + r) * HDIM + c * 8, &sK[(i * 256 + (w << 6)) * 8]);
      g2l16(Vh + r * SS + kb + c * 8, &sV[(i * 256 + (w << 6)) * 8]);
    }
    __syncthreads();

    // S^T per j-tile: C row = key (j*16+qd*4+r), col = q (lm). K-frags read
    // ONCE, used by both q-groups. Mask enters as the accumulator init.
    f16x4 pf[2][4];
#pragma unroll
    for (int j = 0; j < 4; ++j) {
      const int R = j * 16 + lm;
      const bf16x8 k0 = *(const bf16x8*)&sK[(R * 8 + (qd ^ (lm & 7))) * 8];
      const bf16x8 k1 = *(const bf16x8*)&sK[(R * 8 + ((4 + qd) ^ (lm & 7))) * 8];
      const float4 bj = *(const float4*)&mb[kb + j * 16 + qd * 4];
      const f32x4 binit = (f32x4){bj.x, bj.y, bj.z, bj.w};
#pragma unroll
      for (int g = 0; g < 2; ++g) {
        f32x4 t0 = binit;
        t0 = __builtin_amdgcn_mfma_f32_16x16x32_bf16(k0, qf[g][0], t0, 0, 0, 0);
        t0 = __builtin_amdgcn_mfma_f32_16x16x32_bf16(k1, qf[g][1], t0, 0, 0, 0);
        const float p0 = EXP2(t0[0]);
        const float p1 = EXP2(t0[1]);
        const float p2 = EXP2(t0[2]);
        const float p3 = EXP2(t0[3]);
        lsum[g] += (p0 + p1) + (p2 + p3);
        union { hf16x2 v[2]; f16x4 f; } pk;
        pk.v[0] = __builtin_amdgcn_cvt_pkrtz(p0, p1);
        pk.v[1] = __builtin_amdgcn_cvt_pkrtz(p2, p3);
        pf[g][j] = pk.f;
      }
    }

    // O^T += V-frag x P-frag; V-frag read ONCE, feeds both q-groups.
#pragma unroll
    for (int dt = 0; dt < 4; ++dt) {
      const int row = dt * 16 + lm;
#pragma unroll
      for (int j = 0; j < 4; ++j) {
        const int ch = (j * 2 + (qd >> 1)) ^ (lm & 7);
        const f16x4 vf = *(const f16x4*)&sV[row * 64 + ch * 8 + (qd & 1) * 4];
#pragma unroll
        for (int g = 0; g < 2; ++g)
          Od[g][dt] = __builtin_amdgcn_mfma_f32_16x16x16f16(vf, pf[g][j],
                                                            Od[g][dt], 0, 0, 0);
      }
    }
    __syncthreads();
  }

#pragma unroll
  for (int g = 0; g < 2; ++g) {
    float ls = lsum[g];
    ls += __shfl_xor(ls, 16);
    ls += __shfl_xor(ls, 32);
    if (qd == 0) Lp[(b * NHEAD + h) * SS + q0 + g * 16 + lm] = ls;
    // O^T C-layout: lane (qd,lm) holds q=lm(+g*16), dims dt*16 + qd*4 + r
#pragma unroll
    for (int dt = 0; dt < 4; ++dt) {
      ushort4 u;
      u.x = f2bf(Od[g][dt][0]); u.y = f2bf(Od[g][dt][1]);
      u.z = f2bf(Od[g][dt][2]); u.w = f2bf(Od[g][dt][3]);
      *(ushort4*)&Op[(b * SS + q0 + g * 16 + lm) * EMBED + h * HDIM +
                     dt * 16 + qd * 4] = u;
    }
  }
}

// ------- combine: Ob = (P0 + P1) / (l0 + l1), bf16 out -------
__global__ __launch_bounds__(256)
void combine_kernel(const unsigned short* __restrict__ Opart,
                    const float* __restrict__ Lpart,
                    unsigned short* __restrict__ Ob) {
  const int i = blockIdx.x * 256 + threadIdx.x;  // per 8 elems
  const int base = i * 8;
  const int token = base >> 10;       // 0..4095
  const int h = (base >> 6) & 15;
  const int b = token >> 11, q = token & 2047;
  const int lidx = (b * NHEAD + h) * SS + q;
  const float ls = Lpart[lidx] + Lpart[BB * NHEAD * SS + lidx];
  const float rinv = 1.f / ls;
  const ushort4* p0 = (const ushort4*)&Opart[base];
  const ushort4* p1 = (const ushort4*)&Opart[BB * SS * EMBED + base];
  ushort4 o[2];
#pragma unroll
  for (int k = 0; k < 2; ++k) {
    const ushort4 a = p0[k], c = p1[k];
    o[k].x = f2bf((bf2f(a.x) + bf2f(c.x)) * rinv);
    o[k].y = f2bf((bf2f(a.y) + bf2f(c.y)) * rinv);
    o[k].z = f2bf((bf2f(a.z) + bf2f(c.z)) * rinv);
    o[k].w = f2bf((bf2f(a.w) + bf2f(c.w)) * rinv);
  }
  *(ushort4*)&Ob[base] = o[0];
  *(ushort4*)&Ob[base + 4] = o[1];
}

extern "C" void kernel_launch(void* const* d_in, const int* in_sizes, int n_in,
                              void* d_out, int out_size, void* d_ws, size_t ws_size,
                              hipStream_t stream) {
  const float* x  = (const float*)d_in[0];
  const int* mask = (const int*)d_in[1];
  const float* Wq = (const float*)d_in[2];
  const float* bq = (const float*)d_in[3];
  const float* Wk = (const float*)d_in[4];
  const float* bk = (const float*)d_in[5];
  const float* Wv = (const float*)d_in[6];
  const float* bv = (const float*)d_in[7];
  const float* Wo = (const float*)d_in[8];
  const float* bo = (const float*)d_in[9];
  float* out = (float*)d_out;

  char* ws = (char*)d_ws;
  const size_t MB = 1024 * 1024;
  // xb [0,8MB) dead after gemm_qkv -> Ob reuses it (combine writes, gemm_out reads)
  unsigned short* xb  = (unsigned short*)(ws);
  unsigned short* Ob  = (unsigned short*)(ws);
  unsigned short* Wqb = (unsigned short*)(ws + 8 * MB);   // 2MB each
  unsigned short* Wkb = Wqb + 1024 * 1024;
  unsigned short* Wvb = Wkb + 1024 * 1024;
  unsigned short* Wob = Wvb + 1024 * 1024;                 // alive till gemm_out
  unsigned short* Qb  = (unsigned short*)(ws + 16 * MB);  // 8MB
  unsigned short* Kb  = (unsigned short*)(ws + 24 * MB);  // 8MB
  unsigned short* VTb = (unsigned short*)(ws + 32 * MB);  // 8MB (fp16)
  unsigned short* Opart = (unsigned short*)(ws + 40 * MB); // 2 x 8MB bf16
  float* mbb   = (float*)(ws + 56 * MB);                   // 16KB
  float* Lpart = (float*)(ws + 56 * MB + 64 * 1024);       // 2 x 256KB

  cvt5_kernel<<<8196, 256, 0, stream>>>(x, Wq, Wk, Wv, Wo, mask,
                                        xb, Wqb, Wkb, Wvb, Wob, mbb);
  gemm_qkv<<<dim3(256, 3), 256, 0, stream>>>(xb, Wqb, Wkb, Wvb, bq, bk, bv,
                                             Qb, Kb, VTb);
  attn_kernel<<<dim3(16, 16, 4), 256, 0, stream>>>(Qb, Kb, VTb, mbb,
                                                   Opart, Lpart);
  combine_kernel<<<2048, 256, 0, stream>>>(Opart, Lpart, Ob);
  gemm_out<<<256, 256, 0, stream>>>(Wob, Ob, bo, out);
}